// Round 8
// baseline (48.495 us; speedup 1.0000x reference)
//
#include <hip/hip_runtime.h>

#define NOUT 83
#define NHEART 27
#define NLUNG 28

// Block: 256 threads = 4 waves; wave w owns volume b0+w, scans its 2160
// quads (33.75 KB) sequentially, 1 KB per step, 6 loads in flight.
// Position (64*i + l) mod 144 has period 9 in i -> lane keeps acc[i%9]
// (static), merges via 9 LDS RMW (wave-private region, lockstep-safe).
// Softmax runs AFTER streaming (off the launch critical path).
// FC: 16 groups x 16 lanes; group g -> rows o = g + 16k (k<6) x 4 vols.
__global__ __launch_bounds__(256, 6) void bodyavg_scan4(
    const float4* __restrict__ x4,   // [B*2160] quads
    const float* __restrict__ dzh,   // [27,16]
    const float* __restrict__ dzl,   // [28,16]
    const float4* __restrict__ fcw4, // [83,144] quads
    const float* __restrict__ fcb,   // [83]
    float* __restrict__ out,         // [B,83]
    int B)
{
    __shared__ float  attn_lds[NOUT * 17];
    __shared__ float4 xms[4 * 144];          // per-volume slice-SUM

    const int tid = threadIdx.x;
    const int blk = blockIdx.x;
    const int b0  = blk * 4;

    const int w = tid >> 6;       // wave = volume slot 0..3
    const int l = tid & 63;
    const int b = b0 + w;

    // ---- Phase 1: sequential scan, one volume per wave ----
    float4 acc[9];
    #pragma unroll
    for (int j = 0; j < 9; ++j) acc[j] = make_float4(0.f, 0.f, 0.f, 0.f);

    if (b < B) {
        const float4* src = x4 + (size_t)b * 2160 + l;
        // 34 steps i: 5 chunks of 6 (i=0..29), one chunk of 4 (i=30..33,
        // last step covers only 48 quads). j = i mod 9, static per step.
        #pragma unroll
        for (int c = 0; c < 5; ++c) {
            float4 t[6];
            #pragma unroll
            for (int u = 0; u < 6; ++u) t[u] = src[(c * 6 + u) * 64];
            #pragma unroll
            for (int u = 0; u < 6; ++u) {
                const int j = (c * 6 + u) % 9;
                acc[j].x += t[u].x; acc[j].y += t[u].y;
                acc[j].z += t[u].z; acc[j].w += t[u].w;
            }
        }
        {
            float4 t[3];
            #pragma unroll
            for (int u = 0; u < 3; ++u) t[u] = src[(30 + u) * 64];
            #pragma unroll
            for (int u = 0; u < 3; ++u) {
                const int j = (30 + u) % 9;          // 3,4,5
                acc[j].x += t[u].x; acc[j].y += t[u].y;
                acc[j].z += t[u].z; acc[j].w += t[u].w;
            }
            if (l < 48) {                             // i=33, j=6
                const float4 tt = src[33 * 64];
                acc[6].x += tt.x; acc[6].y += tt.y;
                acc[6].z += tt.z; acc[6].w += tt.w;
            }
        }
    }

    // zero own wave's region then merge (wave-private, no barrier needed)
    {
        const float4 z = make_float4(0.f, 0.f, 0.f, 0.f);
        xms[w * 144 + l] = z;
        xms[w * 144 + 64 + l] = z;
        if (l < 16) xms[w * 144 + 128 + l] = z;
    }
    #pragma unroll
    for (int j = 0; j < 9; ++j) {
        int p = (64 * j) % 144 + l;          // < 192
        if (p >= 144) p -= 144;
        const int idx = w * 144 + p;
        float4 cur = xms[idx];
        cur.x += acc[j].x; cur.y += acc[j].y;
        cur.z += acc[j].z; cur.w += acc[j].w;
        xms[idx] = cur;
    }

    // ---- Phase 0 (moved): channel softmax, 1/15 folded in ----
    if (tid < NOUT) {
        const int o = tid;
        const float* row = (o < NHEART) ? (dzh + o * 16)
                                        : (dzl + ((o - NHEART) % NLUNG) * 16);
        float vals[16];
        #pragma unroll
        for (int c = 0; c < 16; ++c) vals[c] = row[c];
        float m = vals[0];
        #pragma unroll
        for (int c = 1; c < 16; ++c) m = fmaxf(m, vals[c]);
        float s = 0.f;
        #pragma unroll
        for (int c = 0; c < 16; ++c) { vals[c] = expf(vals[c] - m); s += vals[c]; }
        const float inv = (1.0f / s) * (1.0f / 15.0f);
        #pragma unroll
        for (int c = 0; c < 16; ++c) attn_lds[o * 17 + c] = vals[c] * inv;
    }

    __syncthreads();

    // ---- Phase 2: FC. 16 groups; group g -> rows o = g + 16k, k=0..5 ----
    const int grp = tid >> 4;     // 0..15
    const int ll  = tid & 15;

    int oc[6];
    const float4* wr[6];
    #pragma unroll
    for (int k = 0; k < 6; ++k) {
        const int o = grp + 16 * k;
        oc[k] = (o < NOUT) ? o : 0;
        wr[k] = fcw4 + oc[k] * 144;
    }

    float facc[6][4] = {};

    #pragma unroll 3
    for (int jj = 0; jj < 9; ++jj) {
        const int q  = ll + 16 * jj;
        const int cc = q / 9;                // channel of this quad

        float4 xv[4];
        #pragma unroll
        for (int v = 0; v < 4; ++v) xv[v] = xms[v * 144 + q];

        #pragma unroll
        for (int k = 0; k < 6; ++k) {
            const float4 wq = wr[k][q];
            const float  a  = attn_lds[oc[k] * 17 + cc];   // includes 1/15
            const float wx = a * wq.x, wy = a * wq.y, wz = a * wq.z, ww = a * wq.w;
            #pragma unroll
            for (int v = 0; v < 4; ++v) {
                facc[k][v] = fmaf(wx, xv[v].x, facc[k][v]);
                facc[k][v] = fmaf(wy, xv[v].y, facc[k][v]);
                facc[k][v] = fmaf(wz, xv[v].z, facc[k][v]);
                facc[k][v] = fmaf(ww, xv[v].w, facc[k][v]);
            }
        }
    }

    // transpose-reduce within 16 lanes: lanes 0-3 end with vols 0-3
    #pragma unroll
    for (int k = 0; k < 6; ++k) {
        float rA[2];
        #pragma unroll
        for (int j = 0; j < 2; ++j) {
            const float lo = facc[k][2 * j], hi = facc[k][2 * j + 1];
            const bool  up = (ll & 1);
            const float keep = up ? hi : lo;
            const float send = up ? lo : hi;
            rA[j] = keep + __shfl_xor(send, 1, 16);
        }
        float r1;
        {
            const float lo = rA[0], hi = rA[1];
            const bool  up = (ll & 2);
            const float keep = up ? hi : lo;
            const float send = up ? lo : hi;
            r1 = keep + __shfl_xor(send, 2, 16);
        }
        r1 += __shfl_xor(r1, 4, 16);
        r1 += __shfl_xor(r1, 8, 16);         // lanes 0-3 hold vols 0-3

        const int o = grp + 16 * k;
        const int bb = b0 + (ll & 3);
        if (ll < 4 && o < NOUT && bb < B)
            out[(size_t)bb * NOUT + o] = r1 + fcb[o];
    }
}

extern "C" void kernel_launch(void* const* d_in, const int* in_sizes, int n_in,
                              void* d_out, int out_size, void* d_ws, size_t ws_size,
                              hipStream_t stream) {
    const float* x   = (const float*)d_in[0];
    const float* dzh = (const float*)d_in[1];
    const float* dzl = (const float*)d_in[2];
    const float* fcw = (const float*)d_in[3];
    const float* fcb = (const float*)d_in[4];
    float* out = (float*)d_out;

    const int B = in_sizes[0] / (15 * 16 * 6 * 6);   // 4096
    const int blocks = (B + 3) / 4;                  // 1024

    hipLaunchKernelGGL(bodyavg_scan4, dim3(blocks), dim3(256), 0, stream,
                       reinterpret_cast<const float4*>(x), dzh, dzl,
                       reinterpret_cast<const float4*>(fcw), fcb, out, B);
}

// Round 9
// 44.402 us; speedup vs baseline: 1.0922x; 1.0922x over previous
//
#include <hip/hip_runtime.h>

#define NOUT 83
#define NHEART 27
#define NLUNG 28

// Block: 256 threads = 4 waves; wave w owns volume b0+w, scans its 2160
// quads (33.75 KB) fully sequentially, 1 KB/step, 9 loads in flight
// (R7's proven streaming inner loop, verbatim).
// Position (64*i + l) mod 144 has period 9 in i -> lane keeps acc[i%9]
// (static), merges via 9 LDS RMW into its wave-private region.
// __launch_bounds__(256,4): VGPR cap 128 (R8's (256,6) capped at 42 and
// strangled the streaming loop - lesson learned).
// FC: 16 groups x 16 lanes; group g -> rows o = g + 16k (k<6) x 4 vols.
__global__ __launch_bounds__(256, 4) void bodyavg_scan4b(
    const float4* __restrict__ x4,   // [B*2160] quads
    const float* __restrict__ dzh,   // [27,16]
    const float* __restrict__ dzl,   // [28,16]
    const float4* __restrict__ fcw4, // [83,144] quads
    const float* __restrict__ fcb,   // [83]
    float* __restrict__ out,         // [B,83]
    int B)
{
    __shared__ float  attn_lds[NOUT * 17];
    __shared__ float4 xms[4 * 144];          // per-volume slice-SUM

    const int tid = threadIdx.x;
    const int blk = blockIdx.x;
    const int b0  = blk * 4;

    const int w = tid >> 6;       // wave = volume slot 0..3
    const int l = tid & 63;
    const int b = b0 + w;

    // ---- Phase 1: sequential scan, one volume per wave (R7 structure) ----
    float4 acc[9];
    #pragma unroll
    for (int j = 0; j < 9; ++j) acc[j] = make_float4(0.f, 0.f, 0.f, 0.f);

    if (b < B) {
        const float4* src = x4 + (size_t)b * 2160 + l;
        // i = 0..26 in three 9-deep chunks (9 loads in flight each)
        #pragma unroll
        for (int c = 0; c < 3; ++c) {
            float4 t[9];
            #pragma unroll
            for (int u = 0; u < 9; ++u) t[u] = src[(c * 9 + u) * 64];
            #pragma unroll
            for (int u = 0; u < 9; ++u) {
                acc[u].x += t[u].x; acc[u].y += t[u].y;
                acc[u].z += t[u].z; acc[u].w += t[u].w;
            }
        }
        // tail i = 27..32 (full), j = i mod 9 = 0..5
        {
            float4 t[6];
            #pragma unroll
            for (int u = 0; u < 6; ++u) t[u] = src[(27 + u) * 64];
            #pragma unroll
            for (int u = 0; u < 6; ++u) {
                acc[u].x += t[u].x; acc[u].y += t[u].y;
                acc[u].z += t[u].z; acc[u].w += t[u].w;
            }
        }
        // i = 33: only 48 quads remain (2160 = 33*64 + 48), j = 6
        if (l < 48) {
            const float4 t = src[33 * 64];
            acc[6].x += t.x; acc[6].y += t.y; acc[6].z += t.z; acc[6].w += t.w;
        }
    }

    // zero own wave's region then merge (wave-private, lockstep-safe)
    {
        const float4 z = make_float4(0.f, 0.f, 0.f, 0.f);
        xms[w * 144 + l] = z;
        xms[w * 144 + 64 + l] = z;
        if (l < 16) xms[w * 144 + 128 + l] = z;
    }
    #pragma unroll
    for (int j = 0; j < 9; ++j) {
        int p = (64 * j) % 144 + l;          // < 192
        if (p >= 144) p -= 144;
        const int idx = w * 144 + p;
        float4 cur = xms[idx];
        cur.x += acc[j].x; cur.y += acc[j].y;
        cur.z += acc[j].z; cur.w += acc[j].w;
        xms[idx] = cur;
    }

    // ---- Phase 0: channel softmax (1/15 folded in), off critical path ----
    if (tid < NOUT) {
        const int o = tid;
        const float* row = (o < NHEART) ? (dzh + o * 16)
                                        : (dzl + ((o - NHEART) % NLUNG) * 16);
        float vals[16];
        #pragma unroll
        for (int c = 0; c < 16; ++c) vals[c] = row[c];
        float m = vals[0];
        #pragma unroll
        for (int c = 1; c < 16; ++c) m = fmaxf(m, vals[c]);
        float s = 0.f;
        #pragma unroll
        for (int c = 0; c < 16; ++c) { vals[c] = expf(vals[c] - m); s += vals[c]; }
        const float inv = (1.0f / s) * (1.0f / 15.0f);
        #pragma unroll
        for (int c = 0; c < 16; ++c) attn_lds[o * 17 + c] = vals[c] * inv;
    }

    __syncthreads();

    // ---- Phase 2: FC. 16 groups; group g -> rows o = g + 16k, k=0..5 ----
    const int grp = tid >> 4;     // 0..15
    const int ll  = tid & 15;

    int oc[6];
    const float4* wr[6];
    #pragma unroll
    for (int k = 0; k < 6; ++k) {
        const int o = grp + 16 * k;
        oc[k] = (o < NOUT) ? o : 0;
        wr[k] = fcw4 + oc[k] * 144;
    }

    float facc[6][4] = {};

    #pragma unroll 3
    for (int jj = 0; jj < 9; ++jj) {
        const int q  = ll + 16 * jj;
        const int cc = q / 9;                // channel of this quad

        float4 xv[4];
        #pragma unroll
        for (int v = 0; v < 4; ++v) xv[v] = xms[v * 144 + q];

        #pragma unroll
        for (int k = 0; k < 6; ++k) {
            const float4 wq = wr[k][q];
            const float  a  = attn_lds[oc[k] * 17 + cc];   // includes 1/15
            const float wx = a * wq.x, wy = a * wq.y, wz = a * wq.z, ww = a * wq.w;
            #pragma unroll
            for (int v = 0; v < 4; ++v) {
                facc[k][v] = fmaf(wx, xv[v].x, facc[k][v]);
                facc[k][v] = fmaf(wy, xv[v].y, facc[k][v]);
                facc[k][v] = fmaf(wz, xv[v].z, facc[k][v]);
                facc[k][v] = fmaf(ww, xv[v].w, facc[k][v]);
            }
        }
    }

    // transpose-reduce within 16 lanes: lanes 0-3 end with vols 0-3
    #pragma unroll
    for (int k = 0; k < 6; ++k) {
        float rA[2];
        #pragma unroll
        for (int j = 0; j < 2; ++j) {
            const float lo = facc[k][2 * j], hi = facc[k][2 * j + 1];
            const bool  up = (ll & 1);
            const float keep = up ? hi : lo;
            const float send = up ? lo : hi;
            rA[j] = keep + __shfl_xor(send, 1, 16);
        }
        float r1;
        {
            const float lo = rA[0], hi = rA[1];
            const bool  up = (ll & 2);
            const float keep = up ? hi : lo;
            const float send = up ? lo : hi;
            r1 = keep + __shfl_xor(send, 2, 16);
        }
        r1 += __shfl_xor(r1, 4, 16);
        r1 += __shfl_xor(r1, 8, 16);         // lanes 0-3 hold vols 0-3

        const int o = grp + 16 * k;
        const int bb = b0 + (ll & 3);
        if (ll < 4 && o < NOUT && bb < B)
            out[(size_t)bb * NOUT + o] = r1 + fcb[o];
    }
}

extern "C" void kernel_launch(void* const* d_in, const int* in_sizes, int n_in,
                              void* d_out, int out_size, void* d_ws, size_t ws_size,
                              hipStream_t stream) {
    const float* x   = (const float*)d_in[0];
    const float* dzh = (const float*)d_in[1];
    const float* dzl = (const float*)d_in[2];
    const float* fcw = (const float*)d_in[3];
    const float* fcb = (const float*)d_in[4];
    float* out = (float*)d_out;

    const int B = in_sizes[0] / (15 * 16 * 6 * 6);   // 4096
    const int blocks = (B + 3) / 4;                  // 1024

    hipLaunchKernelGGL(bodyavg_scan4b, dim3(blocks), dim3(256), 0, stream,
                       reinterpret_cast<const float4*>(x), dzh, dzl,
                       reinterpret_cast<const float4*>(fcw), fcb, out, B);
}

// Round 10
// 35.694 us; speedup vs baseline: 1.3587x; 1.2440x over previous
//
#include <hip/hip_runtime.h>

#define NOUT 83
#define NHEART 27
#define NLUNG 28

typedef float v4f __attribute__((ext_vector_type(4)));

// one 16B global load, literal offset, forced via inline asm (volatile ->
// compiler cannot split the 9-deep chunk or shrink VGPR liveness)
#define GLOAD(dst, ptr, offs) \
    asm volatile("global_load_dwordx4 %0, %1, off offset:" offs \
                 : "=v"(dst) : "v"(ptr))

// Block: 512 threads = 8 waves; wave w owns volume b0+w, scans its 2160
// quads (33.75 KB) sequentially, 1 KB/step. 3 chunks of 9 steps + 6 + 1.
// Chunk: 9 asm loads (9 KB in flight) -> vmcnt(4) consume 5 -> vmcnt(0)
// consume 4. Position (64*i+l) mod 144, period 9 -> acc[i%9] static,
// merged via 9 LDS RMW into the wave-private xms region (lockstep-safe).
// FC: 32 groups x 16 lanes; group g -> rows o = g+32k (k<3) x 8 vols.
__global__ __launch_bounds__(512) void bodyavg_scan8f(
    const v4f* __restrict__ x4,      // [B*2160] quads
    const float* __restrict__ dzh,   // [27,16]
    const float* __restrict__ dzl,   // [28,16]
    const v4f* __restrict__ fcw4,    // [83,144] quads
    const float* __restrict__ fcb,   // [83]
    float* __restrict__ out,         // [B,83]
    int B)
{
    __shared__ float attn_lds[NOUT * 17];
    __shared__ v4f   xms[8 * 144];           // per-volume slice-SUM

    const int tid = threadIdx.x;
    const int blk = blockIdx.x;
    const int b0  = blk * 8;

    const int w = tid >> 6;       // wave = volume slot 0..7
    const int l = tid & 63;
    const int b = b0 + w;

    // ---- Phase 1: sequential scan, one volume per wave, forced 9-deep ----
    v4f acc[9];
    #pragma unroll
    for (int j = 0; j < 9; ++j) acc[j] = (v4f){0.f, 0.f, 0.f, 0.f};

    if (b < B) {
        const v4f* src = x4 + (size_t)b * 2160 + l;
        const v4f* p0 = src;            // steps +0..+3   (offsets 0..3072)
        const v4f* p1 = src + 256;      // steps +4..+7
        const v4f* p2 = src + 512;      // step  +8

        #pragma unroll
        for (int c = 0; c < 3; ++c) {   // steps 0..26
            v4f t0, t1, t2, t3, t4, t5, t6, t7, t8;
            GLOAD(t0, p0, "0");    GLOAD(t1, p0, "1024");
            GLOAD(t2, p0, "2048"); GLOAD(t3, p0, "3072");
            GLOAD(t4, p1, "0");    GLOAD(t5, p1, "1024");
            GLOAD(t6, p1, "2048"); GLOAD(t7, p1, "3072");
            GLOAD(t8, p2, "0");
            asm volatile("s_waitcnt vmcnt(4)" ::: "memory");
            __builtin_amdgcn_sched_barrier(0);
            acc[0] += t0; acc[1] += t1; acc[2] += t2; acc[3] += t3; acc[4] += t4;
            asm volatile("s_waitcnt vmcnt(0)" ::: "memory");
            __builtin_amdgcn_sched_barrier(0);
            acc[5] += t5; acc[6] += t6; acc[7] += t7; acc[8] += t8;
            p0 += 576; p1 += 576; p2 += 576;
        }
        {   // tail steps 27..32 (j = 0..5)
            v4f t0, t1, t2, t3, t4, t5;
            GLOAD(t0, p0, "0");    GLOAD(t1, p0, "1024");
            GLOAD(t2, p0, "2048"); GLOAD(t3, p0, "3072");
            GLOAD(t4, p1, "0");    GLOAD(t5, p1, "1024");
            asm volatile("s_waitcnt vmcnt(0)" ::: "memory");
            __builtin_amdgcn_sched_barrier(0);
            acc[0] += t0; acc[1] += t1; acc[2] += t2;
            acc[3] += t3; acc[4] += t4; acc[5] += t5;
        }
        if (l < 48) acc[6] += src[2112];  // step 33 (partial, j = 6)
    }

    // zero own wave's region then merge (wave-private, lockstep-safe)
    {
        const v4f z = (v4f){0.f, 0.f, 0.f, 0.f};
        xms[w * 144 + l] = z;
        xms[w * 144 + 64 + l] = z;
        if (l < 16) xms[w * 144 + 128 + l] = z;
    }
    #pragma unroll
    for (int j = 0; j < 9; ++j) {
        int p = (64 * j) % 144 + l;      // < 192
        if (p >= 144) p -= 144;
        xms[w * 144 + p] += acc[j];
    }

    // ---- Phase 0: channel softmax (1/15 folded in), off critical path ----
    if (tid < NOUT) {
        const int o = tid;
        const float* row = (o < NHEART) ? (dzh + o * 16)
                                        : (dzl + ((o - NHEART) % NLUNG) * 16);
        float vals[16];
        #pragma unroll
        for (int c = 0; c < 16; ++c) vals[c] = row[c];
        float m = vals[0];
        #pragma unroll
        for (int c = 1; c < 16; ++c) m = fmaxf(m, vals[c]);
        float s = 0.f;
        #pragma unroll
        for (int c = 0; c < 16; ++c) { vals[c] = expf(vals[c] - m); s += vals[c]; }
        const float inv = (1.0f / s) * (1.0f / 15.0f);
        #pragma unroll
        for (int c = 0; c < 16; ++c) attn_lds[o * 17 + c] = vals[c] * inv;
    }

    __syncthreads();

    // ---- Phase 2: FC. 32 groups of 16 lanes; rows o = grp + 32k, k<3 ----
    const int grp = tid >> 4;     // 0..31
    const int ll  = tid & 15;

    int oc[3];
    const v4f* wr[3];
    #pragma unroll
    for (int k = 0; k < 3; ++k) {
        const int o = grp + 32 * k;
        oc[k] = (o < NOUT) ? o : 0;
        wr[k] = fcw4 + oc[k] * 144;
    }

    float facc[3][8] = {};

    #pragma unroll 3
    for (int jj = 0; jj < 9; ++jj) {
        const int q  = ll + 16 * jj;
        const int cc = q / 9;                // channel of this quad

        v4f xv[8];
        #pragma unroll
        for (int v = 0; v < 8; ++v) xv[v] = xms[v * 144 + q];

        #pragma unroll
        for (int k = 0; k < 3; ++k) {
            const v4f  wq = wr[k][q];
            const float a = attn_lds[oc[k] * 17 + cc];   // includes 1/15
            const float wx = a * wq.x, wy = a * wq.y, wz = a * wq.z, ww = a * wq.w;
            #pragma unroll
            for (int v = 0; v < 8; ++v) {
                facc[k][v] = fmaf(wx, xv[v].x, facc[k][v]);
                facc[k][v] = fmaf(wy, xv[v].y, facc[k][v]);
                facc[k][v] = fmaf(wz, xv[v].z, facc[k][v]);
                facc[k][v] = fmaf(ww, xv[v].w, facc[k][v]);
            }
        }
    }

    // transpose-reduce within 16 lanes: lanes 0-7 end with vols 0-7
    #pragma unroll
    for (int k = 0; k < 3; ++k) {
        float r4[4];
        #pragma unroll
        for (int j = 0; j < 4; ++j) {
            const float lo = facc[k][2 * j], hi = facc[k][2 * j + 1];
            const bool  up = (ll & 1);
            const float keep = up ? hi : lo;
            const float send = up ? lo : hi;
            r4[j] = keep + __shfl_xor(send, 1, 16);
        }
        float r2[2];
        #pragma unroll
        for (int j = 0; j < 2; ++j) {
            const float lo = r4[2 * j], hi = r4[2 * j + 1];
            const bool  up = (ll & 2);
            const float keep = up ? hi : lo;
            const float send = up ? lo : hi;
            r2[j] = keep + __shfl_xor(send, 2, 16);
        }
        float r1;
        {
            const float lo = r2[0], hi = r2[1];
            const bool  up = (ll & 4);
            const float keep = up ? hi : lo;
            const float send = up ? lo : hi;
            r1 = keep + __shfl_xor(send, 4, 16);
        }
        r1 += __shfl_xor(r1, 8, 16);         // lanes 0-7 hold vols 0-7

        const int o = grp + 32 * k;
        const int bb = b0 + (ll & 7);
        if (ll < 8 && o < NOUT && bb < B)
            out[(size_t)bb * NOUT + o] = r1 + fcb[o];
    }
}

extern "C" void kernel_launch(void* const* d_in, const int* in_sizes, int n_in,
                              void* d_out, int out_size, void* d_ws, size_t ws_size,
                              hipStream_t stream) {
    const float* x   = (const float*)d_in[0];
    const float* dzh = (const float*)d_in[1];
    const float* dzl = (const float*)d_in[2];
    const float* fcw = (const float*)d_in[3];
    const float* fcb = (const float*)d_in[4];
    float* out = (float*)d_out;

    const int B = in_sizes[0] / (15 * 16 * 6 * 6);   // 4096
    const int blocks = (B + 7) / 8;                  // 512

    hipLaunchKernelGGL(bodyavg_scan8f, dim3(blocks), dim3(512), 0, stream,
                       reinterpret_cast<const v4f*>(x), dzh, dzl,
                       reinterpret_cast<const v4f*>(fcw), fcb, out, B);
}